// Round 3
// baseline (3517.587 us; speedup 1.0000x reference)
//
#include <hip/hip_runtime.h>
#include <hip/hip_bf16.h>

typedef float v2f __attribute__((ext_vector_type(2)));

#define NTOK 8192      // B*S = 32*256
#define DD 16
#define VV 8192
#define VC 1024        // codes per LDS chunk
#define NCHUNK 8
#define TWG 32         // tokens per workgroup
#define TP 4           // token-pairs per wave (8 tokens: tp and tp+4)
#define KS 1.8033688011112042f  // log2(e)/0.8 (temperature fold)

// d_ws layout (float offsets)
#define WS_CBT 0        // cbT[16][8192]
#define WS_B1  131072   // b*KS
#define WS_T1  139264   // t_proj*KS
#define WS_CC2 147456   // ||c||^2

__global__ __launch_bounds__(256) void prep_kernel(
    const float* __restrict__ cb, const float* __restrict__ bm,
    const float* __restrict__ tp, float* __restrict__ ws) {
  __shared__ float tile[256 * 17];   // +1 pad: conflict-free transpose
  float* cbT = ws + WS_CBT;
  float* B1  = ws + WS_B1;
  float* T1  = ws + WS_T1;
  float* CC2 = ws + WS_CC2;
  const int tid = threadIdx.x;
  const int v0 = blockIdx.x * 256;
#pragma unroll
  for (int k = 0; k < 4; k++) {
    int j = tid + (k << 8);          // float4 id in [0,1024)
    int v = j >> 2, d4 = (j & 3) << 2;
    float4 f = *(const float4*)(cb + (size_t)(v0 + v) * DD + d4);
    tile[v * 17 + d4 + 0] = f.x;
    tile[v * 17 + d4 + 1] = f.y;
    tile[v * 17 + d4 + 2] = f.z;
    tile[v * 17 + d4 + 3] = f.w;
  }
  __syncthreads();
#pragma unroll
  for (int k = 0; k < 16; k++) {
    int j = tid + (k << 8);
    int d = j >> 8, c = j & 255;
    cbT[(size_t)d * VV + v0 + c] = tile[c * 17 + d];
  }
  int v = v0 + tid;
  float s = 0.f;
#pragma unroll
  for (int d4 = 0; d4 < DD; d4 += 4) {
    float4 f = *(const float4*)(cb + (size_t)v * DD + d4);
    s += f.x * f.x + f.y * f.y + f.z * f.z + f.w * f.w;
  }
  CC2[v] = s;
  B1[v] = bm[v] * KS;
  T1[v] = tp[v] * KS;
}

__global__ __launch_bounds__(256, 1) void flow_kernel(
    const float* __restrict__ x0, const float* __restrict__ Wm,
    const float* __restrict__ ws, const int* __restrict__ nsp,
    float* __restrict__ out) {
  __shared__ float wL[DD * VC];     // 64 KB  W chunk, d-major
  __shared__ float cL[DD * VC];     // 64 KB  cbT chunk, d-major
  __shared__ float b1L[VC];
  __shared__ float t1L[VC];
  __shared__ float sL[TWG * DD];    // saved state s across midpoint halves

  const float* cbT = ws + WS_CBT;
  const float* B1  = ws + WS_B1;
  const float* T1  = ws + WS_T1;
  const float* CC2 = ws + WS_CC2;

  const int tid = threadIdx.x;
  const int lane = tid & 63;
  const int wave = tid >> 6;
  const int tokBase = blockIdx.x * TWG + wave * 8;

  const int n_steps = *nsp;
  const float dt = 1.0f / (float)(n_steps - 1);

  // state: token-pair packed, comp .x = token tokBase+tp, .y = tokBase+tp+4
  v2f ex2[TP][DD];
#pragma unroll
  for (int t = 0; t < TP; t++) {
#pragma unroll
    for (int d = 0; d < DD; d++) {
      ex2[t][d].x = x0[(size_t)(tokBase + t) * DD + d];
      ex2[t][d].y = x0[(size_t)(tokBase + t + 4) * DD + d];
    }
  }
  if (lane == 0) {
#pragma unroll
    for (int t = 0; t < TP; t++)
#pragma unroll
      for (int d = 0; d < DD; d++) {
        sL[(wave * 8 + t) * DD + d]     = ex2[t][d].x;
        sL[(wave * 8 + t + 4) * DD + d] = ex2[t][d].y;
      }
  }

  for (int step = 0; step < n_steps - 1; step++) {
    const float tbase = (float)step * dt;
#pragma unroll 1
    for (int half = 0; half < 2; half++) {
      const float tt = tbase + (half ? 0.5f * dt : 0.0f);
      v2f acc2[TP][DD];
      v2f l2[TP];
#pragma unroll
      for (int t = 0; t < TP; t++) {
        l2[t] = (v2f){0.f, 0.f};
#pragma unroll
        for (int d = 0; d < DD; d++) acc2[t][d] = (v2f){0.f, 0.f};
      }
#pragma unroll 1
      for (int c = 0; c < NCHUNK; c++) {
        __syncthreads();   // protect LDS from previous chunk's readers
        const int v0 = c * VC;
#pragma unroll
        for (int k = 0; k < 16; k++) {
          int j = tid + (k << 8);
          int row = j >> 8;
          int col = (j & 255) << 2;
          *(float4*)(wL + row * VC + col) =
              *(const float4*)(Wm + (size_t)row * VV + v0 + col);
        }
#pragma unroll
        for (int k = 0; k < 16; k++) {
          int j = tid + (k << 8);
          int row = j >> 8;
          int col = (j & 255) << 2;
          *(float4*)(cL + row * VC + col) =
              *(const float4*)(cbT + (size_t)row * VV + v0 + col);
        }
        {
          int col = tid << 2;
          *(float4*)(b1L + col) = *(const float4*)(B1 + v0 + col);
          *(float4*)(t1L + col) = *(const float4*)(T1 + v0 + col);
        }
        __syncthreads();
#pragma unroll 1
        for (int p = 0; p < 4; p++) {
          const int vb = (p << 8) + (lane << 2);   // 4 consecutive codes / lane
          v2f e2[TP][4];
#pragma unroll
          for (int t = 0; t < TP; t++)
#pragma unroll
            for (int j = 0; j < 4; j++) e2[t][j] = (v2f){0.f, 0.f};
          // logits: e2[t][j] += ex2[t][d] * splat(w[d][vb+j])
#pragma unroll
          for (int d = 0; d < DD; d++) {
            float4 w4 = *(const float4*)(wL + d * VC + vb);
            v2f w0 = {w4.x, w4.x}, w1 = {w4.y, w4.y};
            v2f w2 = {w4.z, w4.z}, w3 = {w4.w, w4.w};
#pragma unroll
            for (int t = 0; t < TP; t++) {
              e2[t][0] = __builtin_elementwise_fma(ex2[t][d], w0, e2[t][0]);
              e2[t][1] = __builtin_elementwise_fma(ex2[t][d], w1, e2[t][1]);
              e2[t][2] = __builtin_elementwise_fma(ex2[t][d], w2, e2[t][2]);
              e2[t][3] = __builtin_elementwise_fma(ex2[t][d], w3, e2[t][3]);
            }
          }
          float4 bb = *(const float4*)(b1L + vb);
          float4 tb = *(const float4*)(t1L + vb);
          v2f bias0 = {fmaf(tt, tb.x, bb.x), fmaf(tt, tb.x, bb.x)};
          v2f bias1 = {fmaf(tt, tb.y, bb.y), fmaf(tt, tb.y, bb.y)};
          v2f bias2 = {fmaf(tt, tb.z, bb.z), fmaf(tt, tb.z, bb.z)};
          v2f bias3 = {fmaf(tt, tb.w, bb.w), fmaf(tt, tb.w, bb.w)};
          const v2f ks2 = {KS, KS};
#pragma unroll
          for (int t = 0; t < TP; t++) {
            e2[t][0] = __builtin_elementwise_fma(e2[t][0], ks2, bias0);
            e2[t][1] = __builtin_elementwise_fma(e2[t][1], ks2, bias1);
            e2[t][2] = __builtin_elementwise_fma(e2[t][2], ks2, bias2);
            e2[t][3] = __builtin_elementwise_fma(e2[t][3], ks2, bias3);
#pragma unroll
            for (int j = 0; j < 4; j++) {
              e2[t][j].x = exp2f(e2[t][j].x);
              e2[t][j].y = exp2f(e2[t][j].y);
            }
            l2[t] += (e2[t][0] + e2[t][1]) + (e2[t][2] + e2[t][3]);
          }
          // acc: acc2[t][d] += e2[t][j] * splat(cb[d][vb+j])
#pragma unroll
          for (int d = 0; d < DD; d++) {
            float4 c4 = *(const float4*)(cL + d * VC + vb);
            v2f c0 = {c4.x, c4.x}, c1 = {c4.y, c4.y};
            v2f c2 = {c4.z, c4.z}, c3 = {c4.w, c4.w};
#pragma unroll
            for (int t = 0; t < TP; t++) {
              v2f a = acc2[t][d];
              a = __builtin_elementwise_fma(e2[t][0], c0, a);
              a = __builtin_elementwise_fma(e2[t][1], c1, a);
              a = __builtin_elementwise_fma(e2[t][2], c2, a);
              a = __builtin_elementwise_fma(e2[t][3], c3, a);
              acc2[t][d] = a;
            }
          }
        }
      }
      // cross-lane merge: per token-pair, per value (small live sets)
      const float inv1 = 1.0f / (1.0f - tt + 1e-10f);
      const float cf = (half == 0) ? (0.5f * dt * inv1) : (dt * inv1);
#pragma unroll 1
      for (int t = 0; t < TP; t++) {
        float lx = l2[t].x, ly = l2[t].y;
#pragma unroll
        for (int m = 1; m < 64; m <<= 1) {
          lx += __shfl_xor(lx, m, 64);
          ly += __shfl_xor(ly, m, 64);
        }
        const float ilx = 1.0f / lx, ily = 1.0f / ly;
#pragma unroll
        for (int d = 0; d < DD; d++) {
          float ax = acc2[t][d].x, ay = acc2[t][d].y;
#pragma unroll
          for (int m = 1; m < 64; m <<= 1) {
            ax += __shfl_xor(ax, m, 64);
            ay += __shfl_xor(ay, m, 64);
          }
          const float mux = ax * ilx, muy = ay * ily;
          if (half == 0) {
            ex2[t][d].x = fmaf(cf, mux - ex2[t][d].x, ex2[t][d].x);
            ex2[t][d].y = fmaf(cf, muy - ex2[t][d].y, ex2[t][d].y);
          } else {
            const float svx = sL[(wave * 8 + t) * DD + d];
            const float svy = sL[(wave * 8 + t + 4) * DD + d];
            ex2[t][d].x = fmaf(cf, mux - ex2[t][d].x, svx);
            ex2[t][d].y = fmaf(cf, muy - ex2[t][d].y, svy);
          }
        }
      }
      if (half == 1) {
        __syncthreads();
        if (lane == 0) {
#pragma unroll
          for (int t = 0; t < TP; t++)
#pragma unroll
            for (int d = 0; d < DD; d++) {
              sL[(wave * 8 + t) * DD + d]     = ex2[t][d].x;
              sL[(wave * 8 + t + 4) * DD + d] = ex2[t][d].y;
            }
        }
      }
    }
  }

  // ---- VQ argmin: d = ||c||^2 - 2 x.c  (pk over token pairs) ----
  v2f minv2[TP];
  int minix[TP], miniy[TP];
#pragma unroll
  for (int t = 0; t < TP; t++) {
    minv2[t] = (v2f){3.402823466e38f, 3.402823466e38f};
    minix[t] = 0; miniy[t] = 0;
  }
#pragma unroll 1
  for (int p = 0; p < 32; p++) {
    const int v4 = (p << 8) + (lane << 2);
    v2f dot2[TP][4];
#pragma unroll
    for (int t = 0; t < TP; t++)
#pragma unroll
      for (int j = 0; j < 4; j++) dot2[t][j] = (v2f){0.f, 0.f};
#pragma unroll
    for (int d = 0; d < DD; d++) {
      float4 c4 = *(const float4*)(cbT + (size_t)d * VV + v4);   // L2-resident
      v2f c0 = {c4.x, c4.x}, c1 = {c4.y, c4.y};
      v2f c2 = {c4.z, c4.z}, c3 = {c4.w, c4.w};
#pragma unroll
      for (int t = 0; t < TP; t++) {
        dot2[t][0] = __builtin_elementwise_fma(ex2[t][d], c0, dot2[t][0]);
        dot2[t][1] = __builtin_elementwise_fma(ex2[t][d], c1, dot2[t][1]);
        dot2[t][2] = __builtin_elementwise_fma(ex2[t][d], c2, dot2[t][2]);
        dot2[t][3] = __builtin_elementwise_fma(ex2[t][d], c3, dot2[t][3]);
      }
    }
    float4 cc = *(const float4*)(CC2 + v4);
#pragma unroll
    for (int t = 0; t < TP; t++) {
#pragma unroll
      for (int j = 0; j < 4; j++) {
        const float ccj = (j == 0) ? cc.x : (j == 1) ? cc.y : (j == 2) ? cc.z : cc.w;
        float dx = fmaf(-2.f, dot2[t][j].x, ccj);
        float dy = fmaf(-2.f, dot2[t][j].y, ccj);
        if (dx < minv2[t].x) { minv2[t].x = dx; minix[t] = v4 + j; }
        if (dy < minv2[t].y) { minv2[t].y = dy; miniy[t] = v4 + j; }
      }
    }
  }
#pragma unroll 1
  for (int t = 0; t < TP; t++) {
#pragma unroll
    for (int m = 1; m < 64; m <<= 1) {
      float ovx = __shfl_xor(minv2[t].x, m, 64);
      int oix = __shfl_xor(minix[t], m, 64);
      if (ovx < minv2[t].x || (ovx == minv2[t].x && oix < minix[t])) {
        minv2[t].x = ovx; minix[t] = oix;
      }
      float ovy = __shfl_xor(minv2[t].y, m, 64);
      int oiy = __shfl_xor(miniy[t], m, 64);
      if (ovy < minv2[t].y || (ovy == minv2[t].y && oiy < miniy[t])) {
        minv2[t].y = ovy; miniy[t] = oiy;
      }
    }
  }

  // ---- outputs (fp32): x_final (131072 floats) then indices-as-float (8192) ----
#pragma unroll
  for (int t = 0; t < TP; t++) {
    if (lane == t) {
      const int tok = tokBase + t;
#pragma unroll
      for (int d = 0; d < DD; d++) out[(size_t)tok * DD + d] = ex2[t][d].x;
      out[(size_t)NTOK * DD + tok] = (float)minix[t];
    }
    if (lane == 8 + t) {
      const int tok = tokBase + t + 4;
#pragma unroll
      for (int d = 0; d < DD; d++) out[(size_t)tok * DD + d] = ex2[t][d].y;
      out[(size_t)NTOK * DD + tok] = (float)miniy[t];
    }
  }
}

extern "C" void kernel_launch(void* const* d_in, const int* in_sizes, int n_in,
                              void* d_out, int out_size, void* d_ws, size_t ws_size,
                              hipStream_t stream) {
  const float* x0 = (const float*)d_in[0];
  const float* cb = (const float*)d_in[1];
  const float* Wm = (const float*)d_in[2];
  const float* bm = (const float*)d_in[3];
  const float* tp = (const float*)d_in[4];
  const int* ns   = (const int*)d_in[5];
  float* ws = (float*)d_ws;               // needs 622592 B
  float* out = (float*)d_out;             // fp32 outputs, concatenated flat

  prep_kernel<<<32, 256, 0, stream>>>(cb, bm, tp, ws);
  flow_kernel<<<256, 256, 0, stream>>>(x0, Wm, ws, ns, out);
}

// Round 4
// 3008.402 us; speedup vs baseline: 1.1693x; 1.1693x over previous
//
#include <hip/hip_runtime.h>

typedef float v2f __attribute__((ext_vector_type(2)));

#define NTOK 8192      // B*S
#define DD 16
#define VV 8192
#define VC 1024        // codes per LDS chunk
#define NCHUNK 8
#define KS 1.8033688011112042f  // log2(e)/0.8

// d_ws layout (float offsets)
#define WS_CBT 0        // cbT[16][8192]
#define WS_B1  131072   // b*KS
#define WS_T1  139264   // t_proj*KS
#define WS_CC2 147456   // ||c||^2

__global__ __launch_bounds__(256) void prep_kernel(
    const float* __restrict__ cb, const float* __restrict__ bm,
    const float* __restrict__ tp, float* __restrict__ ws) {
  __shared__ float tile[256 * 17];
  float* cbT = ws + WS_CBT;
  float* B1  = ws + WS_B1;
  float* T1  = ws + WS_T1;
  float* CC2 = ws + WS_CC2;
  const int tid = threadIdx.x;
  const int v0 = blockIdx.x * 256;
#pragma unroll
  for (int k = 0; k < 4; k++) {
    int j = tid + (k << 8);
    int v = j >> 2, d4 = (j & 3) << 2;
    float4 f = *(const float4*)(cb + (size_t)(v0 + v) * DD + d4);
    tile[v * 17 + d4 + 0] = f.x;
    tile[v * 17 + d4 + 1] = f.y;
    tile[v * 17 + d4 + 2] = f.z;
    tile[v * 17 + d4 + 3] = f.w;
  }
  __syncthreads();
#pragma unroll
  for (int k = 0; k < 16; k++) {
    int j = tid + (k << 8);
    int d = j >> 8, c = j & 255;
    cbT[(size_t)d * VV + v0 + c] = tile[c * 17 + d];
  }
  int v = v0 + tid;
  float s = 0.f;
#pragma unroll
  for (int d4 = 0; d4 < DD; d4 += 4) {
    float4 f = *(const float4*)(cb + (size_t)v * DD + d4);
    s += f.x * f.x + f.y * f.y + f.z * f.z + f.w * f.w;
  }
  CC2[v] = s;
  B1[v] = bm[v] * KS;
  T1[v] = tp[v] * KS;
}

// Half-wave design: lanes 0-31 own tokens [tokBase..tokBase+3], lanes 32-63
// own tokens [tokBase+4..tokBase+7]. Both halves sweep the same code slice
// (mirrored LDS addresses = same-address broadcast, conflict-free).
// Per-lane live set: ex2 64 + acc2 64 + e2 16 ≈ 180 regs -> no scratch spill.
__global__ __launch_bounds__(256, 1) void flow_kernel(
    const float* __restrict__ x0, const float* __restrict__ Wm,
    const float* __restrict__ ws, const int* __restrict__ nsp,
    float* __restrict__ out) {
  __shared__ float wL[DD * VC];     // 64 KB  W chunk, d-major
  __shared__ float cL[DD * VC];     // 64 KB  cbT chunk, d-major
  __shared__ float b1L[VC];
  __shared__ float t1L[VC];
  __shared__ float sL[32 * DD];     // saved state across midpoint halves

  const float* cbT = ws + WS_CBT;
  const float* B1  = ws + WS_B1;
  const float* T1  = ws + WS_T1;
  const float* CC2 = ws + WS_CC2;

  const int tid = threadIdx.x;
  const int lane = tid & 63;
  const int wave = tid >> 6;
  const int half = lane >> 5;          // 0 or 1
  const int hl = lane & 31;            // lane within half
  const int tokBase = blockIdx.x * 32 + wave * 8 + half * 4;  // this half's 4 tokens
  const int sbase = wave * 8 + half * 4;

  const int n_steps = *nsp;
  const float dt = 1.0f / (float)(n_steps - 1);

  // pairs: pair t -> (.x = token tokBase+t, .y = token tokBase+t+2), t in {0,1}
  v2f ex2[2][DD];
#pragma unroll
  for (int t = 0; t < 2; t++) {
#pragma unroll
    for (int d = 0; d < DD; d++) {
      ex2[t][d].x = x0[(size_t)(tokBase + t) * DD + d];
      ex2[t][d].y = x0[(size_t)(tokBase + t + 2) * DD + d];
    }
  }
  if (hl == 0) {
#pragma unroll
    for (int t = 0; t < 2; t++)
#pragma unroll
      for (int d = 0; d < DD; d++) {
        sL[(sbase + t) * DD + d]     = ex2[t][d].x;
        sL[(sbase + t + 2) * DD + d] = ex2[t][d].y;
      }
  }

  for (int step = 0; step < n_steps - 1; step++) {
    const float tbase = (float)step * dt;
#pragma unroll 1
    for (int mh = 0; mh < 2; mh++) {
      const float tt = tbase + (mh ? 0.5f * dt : 0.0f);
      v2f acc2[2][DD];
      v2f l2[2];
#pragma unroll
      for (int t = 0; t < 2; t++) {
        l2[t] = (v2f){0.f, 0.f};
#pragma unroll
        for (int d = 0; d < DD; d++) acc2[t][d] = (v2f){0.f, 0.f};
      }
#pragma unroll 1
      for (int c = 0; c < NCHUNK; c++) {
        __syncthreads();
        const int v0 = c * VC;
#pragma unroll
        for (int k = 0; k < 16; k++) {
          int j = tid + (k << 8);
          int row = j >> 8;
          int col = (j & 255) << 2;
          *(float4*)(wL + row * VC + col) =
              *(const float4*)(Wm + (size_t)row * VV + v0 + col);
        }
#pragma unroll
        for (int k = 0; k < 16; k++) {
          int j = tid + (k << 8);
          int row = j >> 8;
          int col = (j & 255) << 2;
          *(float4*)(cL + row * VC + col) =
              *(const float4*)(cbT + (size_t)row * VV + v0 + col);
        }
        {
          int col = tid << 2;
          *(float4*)(b1L + col) = *(const float4*)(B1 + v0 + col);
          *(float4*)(t1L + col) = *(const float4*)(T1 + v0 + col);
        }
        __syncthreads();
#pragma unroll 1
        for (int p = 0; p < 8; p++) {
          const int vb = (p << 7) + (hl << 2);   // 4 codes/lane, 128 codes/p
          v2f e2[2][4];
#pragma unroll
          for (int t = 0; t < 2; t++)
#pragma unroll
            for (int j = 0; j < 4; j++) e2[t][j] = (v2f){0.f, 0.f};
#pragma unroll
          for (int d = 0; d < DD; d++) {
            float4 w4 = *(const float4*)(wL + d * VC + vb);
            v2f w0 = {w4.x, w4.x}, w1 = {w4.y, w4.y};
            v2f w2 = {w4.z, w4.z}, w3 = {w4.w, w4.w};
#pragma unroll
            for (int t = 0; t < 2; t++) {
              e2[t][0] = __builtin_elementwise_fma(ex2[t][d], w0, e2[t][0]);
              e2[t][1] = __builtin_elementwise_fma(ex2[t][d], w1, e2[t][1]);
              e2[t][2] = __builtin_elementwise_fma(ex2[t][d], w2, e2[t][2]);
              e2[t][3] = __builtin_elementwise_fma(ex2[t][d], w3, e2[t][3]);
            }
          }
          float4 bb = *(const float4*)(b1L + vb);
          float4 tb = *(const float4*)(t1L + vb);
          v2f bias0 = {fmaf(tt, tb.x, bb.x), fmaf(tt, tb.x, bb.x)};
          v2f bias1 = {fmaf(tt, tb.y, bb.y), fmaf(tt, tb.y, bb.y)};
          v2f bias2 = {fmaf(tt, tb.z, bb.z), fmaf(tt, tb.z, bb.z)};
          v2f bias3 = {fmaf(tt, tb.w, bb.w), fmaf(tt, tb.w, bb.w)};
          const v2f ks2 = {KS, KS};
#pragma unroll
          for (int t = 0; t < 2; t++) {
            e2[t][0] = __builtin_elementwise_fma(e2[t][0], ks2, bias0);
            e2[t][1] = __builtin_elementwise_fma(e2[t][1], ks2, bias1);
            e2[t][2] = __builtin_elementwise_fma(e2[t][2], ks2, bias2);
            e2[t][3] = __builtin_elementwise_fma(e2[t][3], ks2, bias3);
#pragma unroll
            for (int j = 0; j < 4; j++) {
              e2[t][j].x = exp2f(e2[t][j].x);
              e2[t][j].y = exp2f(e2[t][j].y);
            }
            l2[t] += (e2[t][0] + e2[t][1]) + (e2[t][2] + e2[t][3]);
          }
#pragma unroll
          for (int d = 0; d < DD; d++) {
            float4 c4 = *(const float4*)(cL + d * VC + vb);
            v2f c0 = {c4.x, c4.x}, c1 = {c4.y, c4.y};
            v2f c2 = {c4.z, c4.z}, c3 = {c4.w, c4.w};
#pragma unroll
            for (int t = 0; t < 2; t++) {
              v2f a = acc2[t][d];
              a = __builtin_elementwise_fma(e2[t][0], c0, a);
              a = __builtin_elementwise_fma(e2[t][1], c1, a);
              a = __builtin_elementwise_fma(e2[t][2], c2, a);
              a = __builtin_elementwise_fma(e2[t][3], c3, a);
              acc2[t][d] = a;
            }
          }
        }
      }
      // butterfly over the 32 lanes of this half (masks 1..16 stay in-half)
      const float inv1 = 1.0f / (1.0f - tt + 1e-10f);
      const float cf = (mh == 0) ? (0.5f * dt * inv1) : (dt * inv1);
#pragma unroll 1
      for (int t = 0; t < 2; t++) {
        float lx = l2[t].x, ly = l2[t].y;
#pragma unroll
        for (int m = 1; m < 32; m <<= 1) {
          lx += __shfl_xor(lx, m, 64);
          ly += __shfl_xor(ly, m, 64);
        }
        const float ilx = 1.0f / lx, ily = 1.0f / ly;
#pragma unroll
        for (int d = 0; d < DD; d++) {
          float ax = acc2[t][d].x, ay = acc2[t][d].y;
#pragma unroll
          for (int m = 1; m < 32; m <<= 1) {
            ax += __shfl_xor(ax, m, 64);
            ay += __shfl_xor(ay, m, 64);
          }
          const float mux = ax * ilx, muy = ay * ily;
          if (mh == 0) {
            ex2[t][d].x = fmaf(cf, mux - ex2[t][d].x, ex2[t][d].x);
            ex2[t][d].y = fmaf(cf, muy - ex2[t][d].y, ex2[t][d].y);
          } else {
            const float svx = sL[(sbase + t) * DD + d];
            const float svy = sL[(sbase + t + 2) * DD + d];
            ex2[t][d].x = fmaf(cf, mux - ex2[t][d].x, svx);
            ex2[t][d].y = fmaf(cf, muy - ex2[t][d].y, svy);
          }
        }
      }
      if (mh == 1) {
        __syncthreads();
        if (hl == 0) {
#pragma unroll
          for (int t = 0; t < 2; t++)
#pragma unroll
            for (int d = 0; d < DD; d++) {
              sL[(sbase + t) * DD + d]     = ex2[t][d].x;
              sL[(sbase + t + 2) * DD + d] = ex2[t][d].y;
            }
        }
      }
    }
  }

  // ---- VQ argmin: d = ||c||^2 - 2 x.c ----
  v2f minv2[2];
  int minix[2], miniy[2];
#pragma unroll
  for (int t = 0; t < 2; t++) {
    minv2[t] = (v2f){3.402823466e38f, 3.402823466e38f};
    minix[t] = 0; miniy[t] = 0;
  }
#pragma unroll 1
  for (int p = 0; p < 64; p++) {
    const int v4 = (p << 7) + (hl << 2);
    v2f dot2[2][4];
#pragma unroll
    for (int t = 0; t < 2; t++)
#pragma unroll
      for (int j = 0; j < 4; j++) dot2[t][j] = (v2f){0.f, 0.f};
#pragma unroll
    for (int d = 0; d < DD; d++) {
      float4 c4 = *(const float4*)(cbT + (size_t)d * VV + v4);   // L2/L3-resident
      v2f c0 = {c4.x, c4.x}, c1 = {c4.y, c4.y};
      v2f c2 = {c4.z, c4.z}, c3 = {c4.w, c4.w};
#pragma unroll
      for (int t = 0; t < 2; t++) {
        dot2[t][0] = __builtin_elementwise_fma(ex2[t][d], c0, dot2[t][0]);
        dot2[t][1] = __builtin_elementwise_fma(ex2[t][d], c1, dot2[t][1]);
        dot2[t][2] = __builtin_elementwise_fma(ex2[t][d], c2, dot2[t][2]);
        dot2[t][3] = __builtin_elementwise_fma(ex2[t][d], c3, dot2[t][3]);
      }
    }
    float4 cc = *(const float4*)(CC2 + v4);
#pragma unroll
    for (int t = 0; t < 2; t++) {
#pragma unroll
      for (int j = 0; j < 4; j++) {
        const float ccj = (j == 0) ? cc.x : (j == 1) ? cc.y : (j == 2) ? cc.z : cc.w;
        float dx = fmaf(-2.f, dot2[t][j].x, ccj);
        float dy = fmaf(-2.f, dot2[t][j].y, ccj);
        if (dx < minv2[t].x) { minv2[t].x = dx; minix[t] = v4 + j; }
        if (dy < minv2[t].y) { minv2[t].y = dy; miniy[t] = v4 + j; }
      }
    }
  }
#pragma unroll 1
  for (int t = 0; t < 2; t++) {
#pragma unroll
    for (int m = 1; m < 32; m <<= 1) {
      float ovx = __shfl_xor(minv2[t].x, m, 64);
      int oix = __shfl_xor(minix[t], m, 64);
      if (ovx < minv2[t].x || (ovx == minv2[t].x && oix < minix[t])) {
        minv2[t].x = ovx; minix[t] = oix;
      }
      float ovy = __shfl_xor(minv2[t].y, m, 64);
      int oiy = __shfl_xor(miniy[t], m, 64);
      if (ovy < minv2[t].y || (ovy == minv2[t].y && oiy < miniy[t])) {
        minv2[t].y = ovy; miniy[t] = oiy;
      }
    }
  }

  // ---- outputs (fp32): x_final (131072) then indices-as-float (8192) ----
  // all 32 lanes of a half hold identical reduced results; lanes 0..3 of the
  // half write its 4 tokens
#pragma unroll
  for (int t = 0; t < 2; t++) {
    if (hl == t) {
      const int tok = tokBase + t;
#pragma unroll
      for (int d = 0; d < DD; d++) out[(size_t)tok * DD + d] = ex2[t][d].x;
      out[(size_t)NTOK * DD + tok] = (float)minix[t];
    }
    if (hl == 2 + t) {
      const int tok = tokBase + t + 2;
#pragma unroll
      for (int d = 0; d < DD; d++) out[(size_t)tok * DD + d] = ex2[t][d].y;
      out[(size_t)NTOK * DD + tok] = (float)miniy[t];
    }
  }
}

extern "C" void kernel_launch(void* const* d_in, const int* in_sizes, int n_in,
                              void* d_out, int out_size, void* d_ws, size_t ws_size,
                              hipStream_t stream) {
  const float* x0 = (const float*)d_in[0];
  const float* cb = (const float*)d_in[1];
  const float* Wm = (const float*)d_in[2];
  const float* bm = (const float*)d_in[3];
  const float* tp = (const float*)d_in[4];
  const int* ns   = (const int*)d_in[5];
  float* ws = (float*)d_ws;               // needs 622592 B
  float* out = (float*)d_out;             // fp32 outputs, concatenated flat

  prep_kernel<<<32, 256, 0, stream>>>(cb, bm, tp, ws);
  flow_kernel<<<256, 256, 0, stream>>>(x0, Wm, ws, ns, out);
}

// Round 5
// 2115.481 us; speedup vs baseline: 1.6628x; 1.4221x over previous
//
#include <hip/hip_runtime.h>

typedef float v2f __attribute__((ext_vector_type(2)));

#define NTOK 8192      // B*S
#define DD 16
#define VV 8192
#define VC 1024        // codes per LDS chunk
#define NCHUNK 8
#define KS 1.8033688011112042f  // log2(e)/0.8

// d_ws layout (float offsets)
#define WS_CBT 0        // cbT[16][8192]
#define WS_B1  131072   // b*KS
#define WS_T1  139264   // t_proj*KS
#define WS_CC2 147456   // ||c||^2

__global__ __launch_bounds__(256) void prep_kernel(
    const float* __restrict__ cb, const float* __restrict__ bm,
    const float* __restrict__ tp, float* __restrict__ ws) {
  __shared__ float tile[256 * 17];
  float* cbT = ws + WS_CBT;
  float* B1  = ws + WS_B1;
  float* T1  = ws + WS_T1;
  float* CC2 = ws + WS_CC2;
  const int tid = threadIdx.x;
  const int v0 = blockIdx.x * 256;
#pragma unroll
  for (int k = 0; k < 4; k++) {
    int j = tid + (k << 8);
    int v = j >> 2, d4 = (j & 3) << 2;
    float4 f = *(const float4*)(cb + (size_t)(v0 + v) * DD + d4);
    tile[v * 17 + d4 + 0] = f.x;
    tile[v * 17 + d4 + 1] = f.y;
    tile[v * 17 + d4 + 2] = f.z;
    tile[v * 17 + d4 + 3] = f.w;
  }
  __syncthreads();
#pragma unroll
  for (int k = 0; k < 16; k++) {
    int j = tid + (k << 8);
    int d = j >> 8, c = j & 255;
    cbT[(size_t)d * VV + v0 + c] = tile[c * 17 + d];
  }
  int v = v0 + tid;
  float s = 0.f;
#pragma unroll
  for (int d4 = 0; d4 < DD; d4 += 4) {
    float4 f = *(const float4*)(cb + (size_t)v * DD + d4);
    s += f.x * f.x + f.y * f.y + f.z * f.z + f.w * f.w;
  }
  CC2[v] = s;
  B1[v] = bm[v] * KS;
  T1[v] = tp[v] * KS;
}

// Half-wave design: lanes 0-31 own tokens [tokBase..+3], lanes 32-63 own
// [tokBase+4..+7]; both halves sweep the same code slice (same-address LDS
// broadcast, conflict-free). CRITICAL: every loop that indexes a private
// array (ex2/acc2/l2/minv2/...) must be FULLY UNROLLED — any runtime index
// demotes the whole array to scratch (R3/R4: 2-4 GB of scratch traffic).
__global__ __launch_bounds__(256, 1) void flow_kernel(
    const float* __restrict__ x0, const float* __restrict__ Wm,
    const float* __restrict__ ws, const int* __restrict__ nsp,
    float* __restrict__ out) {
  __shared__ float wL[DD * VC];     // 64 KB  W chunk, d-major
  __shared__ float cL[DD * VC];     // 64 KB  cbT chunk, d-major
  __shared__ float b1L[VC];
  __shared__ float t1L[VC];
  __shared__ float sL[32 * DD];     // saved state across midpoint halves

  const float* cbT = ws + WS_CBT;
  const float* B1  = ws + WS_B1;
  const float* T1  = ws + WS_T1;
  const float* CC2 = ws + WS_CC2;

  const int tid = threadIdx.x;
  const int lane = tid & 63;
  const int wave = tid >> 6;
  const int half = lane >> 5;          // 0 or 1
  const int hl = lane & 31;            // lane within half
  const int tokBase = blockIdx.x * 32 + wave * 8 + half * 4;
  const int sbase = wave * 8 + half * 4;

  const int n_steps = *nsp;
  const float dt = 1.0f / (float)(n_steps - 1);

  // pair t -> (.x = token tokBase+t, .y = token tokBase+t+2), t in {0,1}
  v2f ex2[2][DD];
#pragma unroll
  for (int t = 0; t < 2; t++) {
#pragma unroll
    for (int d = 0; d < DD; d++) {
      ex2[t][d].x = x0[(size_t)(tokBase + t) * DD + d];
      ex2[t][d].y = x0[(size_t)(tokBase + t + 2) * DD + d];
    }
  }
  if (hl == 0) {
#pragma unroll
    for (int t = 0; t < 2; t++)
#pragma unroll
      for (int d = 0; d < DD; d++) {
        sL[(sbase + t) * DD + d]     = ex2[t][d].x;
        sL[(sbase + t + 2) * DD + d] = ex2[t][d].y;
      }
  }

  for (int step = 0; step < n_steps - 1; step++) {
    const float tbase = (float)step * dt;
#pragma unroll 1
    for (int mh = 0; mh < 2; mh++) {
      const float tt = tbase + (mh ? 0.5f * dt : 0.0f);
      v2f acc2[2][DD];
      v2f l2[2];
#pragma unroll
      for (int t = 0; t < 2; t++) {
        l2[t] = (v2f){0.f, 0.f};
#pragma unroll
        for (int d = 0; d < DD; d++) acc2[t][d] = (v2f){0.f, 0.f};
      }
#pragma unroll 1
      for (int c = 0; c < NCHUNK; c++) {
        __syncthreads();
        const int v0 = c * VC;
#pragma unroll
        for (int k = 0; k < 16; k++) {
          int j = tid + (k << 8);
          int row = j >> 8;
          int col = (j & 255) << 2;
          *(float4*)(wL + row * VC + col) =
              *(const float4*)(Wm + (size_t)row * VV + v0 + col);
        }
#pragma unroll
        for (int k = 0; k < 16; k++) {
          int j = tid + (k << 8);
          int row = j >> 8;
          int col = (j & 255) << 2;
          *(float4*)(cL + row * VC + col) =
              *(const float4*)(cbT + (size_t)row * VV + v0 + col);
        }
        {
          int col = tid << 2;
          *(float4*)(b1L + col) = *(const float4*)(B1 + v0 + col);
          *(float4*)(t1L + col) = *(const float4*)(T1 + v0 + col);
        }
        __syncthreads();
#pragma unroll 1
        for (int p = 0; p < 8; p++) {
          const int vb = (p << 7) + (hl << 2);   // 4 codes/lane, 128 codes/p
          v2f e2[2][4];
#pragma unroll
          for (int t = 0; t < 2; t++)
#pragma unroll
            for (int j = 0; j < 4; j++) e2[t][j] = (v2f){0.f, 0.f};
#pragma unroll
          for (int d = 0; d < DD; d++) {
            float4 w4 = *(const float4*)(wL + d * VC + vb);
            v2f w0 = {w4.x, w4.x}, w1 = {w4.y, w4.y};
            v2f w2 = {w4.z, w4.z}, w3 = {w4.w, w4.w};
#pragma unroll
            for (int t = 0; t < 2; t++) {
              e2[t][0] = __builtin_elementwise_fma(ex2[t][d], w0, e2[t][0]);
              e2[t][1] = __builtin_elementwise_fma(ex2[t][d], w1, e2[t][1]);
              e2[t][2] = __builtin_elementwise_fma(ex2[t][d], w2, e2[t][2]);
              e2[t][3] = __builtin_elementwise_fma(ex2[t][d], w3, e2[t][3]);
            }
          }
          float4 bb = *(const float4*)(b1L + vb);
          float4 tb = *(const float4*)(t1L + vb);
          v2f bias0 = {fmaf(tt, tb.x, bb.x), fmaf(tt, tb.x, bb.x)};
          v2f bias1 = {fmaf(tt, tb.y, bb.y), fmaf(tt, tb.y, bb.y)};
          v2f bias2 = {fmaf(tt, tb.z, bb.z), fmaf(tt, tb.z, bb.z)};
          v2f bias3 = {fmaf(tt, tb.w, bb.w), fmaf(tt, tb.w, bb.w)};
          const v2f ks2 = {KS, KS};
#pragma unroll
          for (int t = 0; t < 2; t++) {
            e2[t][0] = __builtin_elementwise_fma(e2[t][0], ks2, bias0);
            e2[t][1] = __builtin_elementwise_fma(e2[t][1], ks2, bias1);
            e2[t][2] = __builtin_elementwise_fma(e2[t][2], ks2, bias2);
            e2[t][3] = __builtin_elementwise_fma(e2[t][3], ks2, bias3);
#pragma unroll
            for (int j = 0; j < 4; j++) {
              e2[t][j].x = exp2f(e2[t][j].x);
              e2[t][j].y = exp2f(e2[t][j].y);
            }
            l2[t] += (e2[t][0] + e2[t][1]) + (e2[t][2] + e2[t][3]);
          }
#pragma unroll
          for (int d = 0; d < DD; d++) {
            float4 c4 = *(const float4*)(cL + d * VC + vb);
            v2f c0 = {c4.x, c4.x}, c1 = {c4.y, c4.y};
            v2f c2 = {c4.z, c4.z}, c3 = {c4.w, c4.w};
#pragma unroll
            for (int t = 0; t < 2; t++) {
              v2f a = acc2[t][d];
              a = __builtin_elementwise_fma(e2[t][0], c0, a);
              a = __builtin_elementwise_fma(e2[t][1], c1, a);
              a = __builtin_elementwise_fma(e2[t][2], c2, a);
              a = __builtin_elementwise_fma(e2[t][3], c3, a);
              acc2[t][d] = a;
            }
          }
        }
      }
      // butterfly over the 32 lanes of this half — FULLY UNROLLED
      const float inv1 = 1.0f / (1.0f - tt + 1e-10f);
      const float cf = (mh == 0) ? (0.5f * dt * inv1) : (dt * inv1);
#pragma unroll
      for (int t = 0; t < 2; t++) {
        float lx = l2[t].x, ly = l2[t].y;
#pragma unroll
        for (int m = 1; m < 32; m <<= 1) {
          lx += __shfl_xor(lx, m, 64);
          ly += __shfl_xor(ly, m, 64);
        }
        const float ilx = 1.0f / lx, ily = 1.0f / ly;
#pragma unroll
        for (int d = 0; d < DD; d++) {
          float ax = acc2[t][d].x, ay = acc2[t][d].y;
#pragma unroll
          for (int m = 1; m < 32; m <<= 1) {
            ax += __shfl_xor(ax, m, 64);
            ay += __shfl_xor(ay, m, 64);
          }
          const float mux = ax * ilx, muy = ay * ily;
          if (mh == 0) {
            ex2[t][d].x = fmaf(cf, mux - ex2[t][d].x, ex2[t][d].x);
            ex2[t][d].y = fmaf(cf, muy - ex2[t][d].y, ex2[t][d].y);
          } else {
            const float svx = sL[(sbase + t) * DD + d];
            const float svy = sL[(sbase + t + 2) * DD + d];
            ex2[t][d].x = fmaf(cf, mux - ex2[t][d].x, svx);
            ex2[t][d].y = fmaf(cf, muy - ex2[t][d].y, svy);
          }
        }
      }
      if (mh == 1) {
        __syncthreads();
        if (hl == 0) {
#pragma unroll
          for (int t = 0; t < 2; t++)
#pragma unroll
            for (int d = 0; d < DD; d++) {
              sL[(sbase + t) * DD + d]     = ex2[t][d].x;
              sL[(sbase + t + 2) * DD + d] = ex2[t][d].y;
            }
        }
      }
    }
  }

  // ---- VQ argmin: d = ||c||^2 - 2 x.c ----
  v2f minv2[2];
  int minix[2], miniy[2];
#pragma unroll
  for (int t = 0; t < 2; t++) {
    minv2[t] = (v2f){3.402823466e38f, 3.402823466e38f};
    minix[t] = 0; miniy[t] = 0;
  }
#pragma unroll 1
  for (int p = 0; p < 64; p++) {
    const int v4 = (p << 7) + (hl << 2);
    v2f dot2[2][4];
#pragma unroll
    for (int t = 0; t < 2; t++)
#pragma unroll
      for (int j = 0; j < 4; j++) dot2[t][j] = (v2f){0.f, 0.f};
#pragma unroll
    for (int d = 0; d < DD; d++) {
      float4 c4 = *(const float4*)(cbT + (size_t)d * VV + v4);   // L2/L3-resident
      v2f c0 = {c4.x, c4.x}, c1 = {c4.y, c4.y};
      v2f c2 = {c4.z, c4.z}, c3 = {c4.w, c4.w};
#pragma unroll
      for (int t = 0; t < 2; t++) {
        dot2[t][0] = __builtin_elementwise_fma(ex2[t][d], c0, dot2[t][0]);
        dot2[t][1] = __builtin_elementwise_fma(ex2[t][d], c1, dot2[t][1]);
        dot2[t][2] = __builtin_elementwise_fma(ex2[t][d], c2, dot2[t][2]);
        dot2[t][3] = __builtin_elementwise_fma(ex2[t][d], c3, dot2[t][3]);
      }
    }
    float4 cc = *(const float4*)(CC2 + v4);
#pragma unroll
    for (int t = 0; t < 2; t++) {
#pragma unroll
      for (int j = 0; j < 4; j++) {
        const float ccj = (j == 0) ? cc.x : (j == 1) ? cc.y : (j == 2) ? cc.z : cc.w;
        float dx = fmaf(-2.f, dot2[t][j].x, ccj);
        float dy = fmaf(-2.f, dot2[t][j].y, ccj);
        if (dx < minv2[t].x) { minv2[t].x = dx; minix[t] = v4 + j; }
        if (dy < minv2[t].y) { minv2[t].y = dy; miniy[t] = v4 + j; }
      }
    }
  }
#pragma unroll
  for (int t = 0; t < 2; t++) {
#pragma unroll
    for (int m = 1; m < 32; m <<= 1) {
      float ovx = __shfl_xor(minv2[t].x, m, 64);
      int oix = __shfl_xor(minix[t], m, 64);
      if (ovx < minv2[t].x || (ovx == minv2[t].x && oix < minix[t])) {
        minv2[t].x = ovx; minix[t] = oix;
      }
      float ovy = __shfl_xor(minv2[t].y, m, 64);
      int oiy = __shfl_xor(miniy[t], m, 64);
      if (ovy < minv2[t].y || (ovy == minv2[t].y && oiy < miniy[t])) {
        minv2[t].y = ovy; miniy[t] = oiy;
      }
    }
  }

  // ---- outputs (fp32): x_final (131072) then indices-as-float (8192) ----
#pragma unroll
  for (int t = 0; t < 2; t++) {
    if (hl == t) {
      const int tok = tokBase + t;
#pragma unroll
      for (int d = 0; d < DD; d++) out[(size_t)tok * DD + d] = ex2[t][d].x;
      out[(size_t)NTOK * DD + tok] = (float)minix[t];
    }
    if (hl == 2 + t) {
      const int tok = tokBase + t + 2;
#pragma unroll
      for (int d = 0; d < DD; d++) out[(size_t)tok * DD + d] = ex2[t][d].y;
      out[(size_t)NTOK * DD + tok] = (float)miniy[t];
    }
  }
}

extern "C" void kernel_launch(void* const* d_in, const int* in_sizes, int n_in,
                              void* d_out, int out_size, void* d_ws, size_t ws_size,
                              hipStream_t stream) {
  const float* x0 = (const float*)d_in[0];
  const float* cb = (const float*)d_in[1];
  const float* Wm = (const float*)d_in[2];
  const float* bm = (const float*)d_in[3];
  const float* tp = (const float*)d_in[4];
  const int* ns   = (const int*)d_in[5];
  float* ws = (float*)d_ws;               // needs 622592 B
  float* out = (float*)d_out;             // fp32 outputs, concatenated flat

  prep_kernel<<<32, 256, 0, stream>>>(cb, bm, tp, ws);
  flow_kernel<<<256, 256, 0, stream>>>(x0, Wm, ws, ns, out);
}

// Round 6
// 1615.072 us; speedup vs baseline: 2.1780x; 1.3098x over previous
//
#include <hip/hip_runtime.h>

typedef float v2f __attribute__((ext_vector_type(2)));

#define NTOK 8192      // B*S
#define DD 16
#define VV 8192
#define VC 1024        // codes per LDS chunk
#define NCHUNK 8
#define KS 1.8033688011112042f  // log2(e)/0.8

// d_ws layout (float offsets)
#define WS_CBT 0        // cbT[16][8192]
#define WS_B1  131072   // b*KS
#define WS_T1  139264   // t_proj*KS
#define WS_CC2 147456   // ||c||^2

__global__ __launch_bounds__(256) void prep_kernel(
    const float* __restrict__ cb, const float* __restrict__ bm,
    const float* __restrict__ tp, float* __restrict__ ws) {
  __shared__ float tile[256 * 17];
  float* cbT = ws + WS_CBT;
  float* B1  = ws + WS_B1;
  float* T1  = ws + WS_T1;
  float* CC2 = ws + WS_CC2;
  const int tid = threadIdx.x;
  const int v0 = blockIdx.x * 256;
#pragma unroll
  for (int k = 0; k < 4; k++) {
    int j = tid + (k << 8);
    int v = j >> 2, d4 = (j & 3) << 2;
    float4 f = *(const float4*)(cb + (size_t)(v0 + v) * DD + d4);
    tile[v * 17 + d4 + 0] = f.x;
    tile[v * 17 + d4 + 1] = f.y;
    tile[v * 17 + d4 + 2] = f.z;
    tile[v * 17 + d4 + 3] = f.w;
  }
  __syncthreads();
#pragma unroll
  for (int k = 0; k < 16; k++) {
    int j = tid + (k << 8);
    int d = j >> 8, c = j & 255;
    cbT[(size_t)d * VV + v0 + c] = tile[c * 17 + d];
  }
  int v = v0 + tid;
  float s = 0.f;
#pragma unroll
  for (int d4 = 0; d4 < DD; d4 += 4) {
    float4 f = *(const float4*)(cb + (size_t)v * DD + d4);
    s += f.x * f.x + f.y * f.y + f.z * f.z + f.w * f.w;
  }
  CC2[v] = s;
  B1[v] = bm[v] * KS;
  T1[v] = tp[v] * KS;
}

// Wave-pair design for occupancy (R5 was 1 wave/SIMD, latency-bound at
// VALUBusy 34%): 512 threads = 8 waves = 2 waves/SIMD. Waves 2k,2k+1 own the
// same 8 tokens; wave parity o sweeps codes [o*512,(o+1)*512) of each chunk.
// Partials merged across the pair via small LDS exchange.
// Half-wave token split as R5: lanes 0-31 tokens [base..+3], 32-63 [+4..+7].
// CRITICAL (R3/R4 lesson): every private-array-indexing loop fully unrolled,
// else the array is demoted to scratch (GBs of FETCH/WRITE traffic).
__global__ __launch_bounds__(512, 2) void flow_kernel(
    const float* __restrict__ x0, const float* __restrict__ Wm,
    const float* __restrict__ ws, const int* __restrict__ nsp,
    float* __restrict__ out) {
  __shared__ float wL[DD * VC];       // 64 KB  W chunk, d-major
  __shared__ float cL[DD * VC];       // 64 KB  cbT chunk, d-major
  __shared__ float b1L[VC];           // 4 KB
  __shared__ float t1L[VC];           // 4 KB
  __shared__ float sL[32 * DD];       // 2 KB saved state across midpoint halves
  __shared__ float4 redP[8][2][17];   // 4.25 KB cross-wave partial exchange
  __shared__ float redMv[8][2][4];    // VQ argmin exchange
  __shared__ int   redMi[8][2][4];

  const float* cbT = ws + WS_CBT;
  const float* B1  = ws + WS_B1;
  const float* T1  = ws + WS_T1;
  const float* CC2 = ws + WS_CC2;

  const int tid = threadIdx.x;
  const int lane = tid & 63;
  const int wave = tid >> 6;           // 0..7
  const int o = wave & 1;              // parity: which half of the code range
  const int wp = wave >> 1;            // pair id 0..3
  const int half = lane >> 5;          // 0 or 1
  const int hl = lane & 31;            // lane within half
  const int tokBase = blockIdx.x * 32 + wp * 8 + half * 4;
  const int sbase = wp * 8 + half * 4;

  const int n_steps = *nsp;
  const float dt = 1.0f / (float)(n_steps - 1);

  // pair t -> (.x = token tokBase+t, .y = token tokBase+t+2), t in {0,1}
  v2f ex2[2][DD];
#pragma unroll
  for (int t = 0; t < 2; t++) {
#pragma unroll
    for (int d = 0; d < DD; d++) {
      ex2[t][d].x = x0[(size_t)(tokBase + t) * DD + d];
      ex2[t][d].y = x0[(size_t)(tokBase + t + 2) * DD + d];
    }
  }
  if (o == 0 && hl == 0) {
#pragma unroll
    for (int t = 0; t < 2; t++)
#pragma unroll
      for (int d = 0; d < DD; d++) {
        sL[(sbase + t) * DD + d]     = ex2[t][d].x;
        sL[(sbase + t + 2) * DD + d] = ex2[t][d].y;
      }
  }

  for (int step = 0; step < n_steps - 1; step++) {
    const float tbase = (float)step * dt;
#pragma unroll 1
    for (int mh = 0; mh < 2; mh++) {
      const float tt = tbase + (mh ? 0.5f * dt : 0.0f);
      v2f acc2[2][DD];
      v2f l2[2];
#pragma unroll
      for (int t = 0; t < 2; t++) {
        l2[t] = (v2f){0.f, 0.f};
#pragma unroll
        for (int d = 0; d < DD; d++) acc2[t][d] = (v2f){0.f, 0.f};
      }
#pragma unroll 1
      for (int c = 0; c < NCHUNK; c++) {
        __syncthreads();
        const int v0 = c * VC;
#pragma unroll
        for (int k = 0; k < 8; k++) {
          int j = tid + (k << 9);
          int row = j >> 8;
          int col = (j & 255) << 2;
          *(float4*)(wL + row * VC + col) =
              *(const float4*)(Wm + (size_t)row * VV + v0 + col);
        }
#pragma unroll
        for (int k = 0; k < 8; k++) {
          int j = tid + (k << 9);
          int row = j >> 8;
          int col = (j & 255) << 2;
          *(float4*)(cL + row * VC + col) =
              *(const float4*)(cbT + (size_t)row * VV + v0 + col);
        }
        {
          int col = (tid & 255) << 2;
          if (tid < 256) *(float4*)(b1L + col) = *(const float4*)(B1 + v0 + col);
          else           *(float4*)(t1L + col) = *(const float4*)(T1 + v0 + col);
        }
        __syncthreads();
#pragma unroll 1
        for (int p = 0; p < 4; p++) {
          const int vb = (o << 9) + (p << 7) + (hl << 2);  // this wave's 4 codes
          v2f e2[2][4];
#pragma unroll
          for (int t = 0; t < 2; t++)
#pragma unroll
            for (int j = 0; j < 4; j++) e2[t][j] = (v2f){0.f, 0.f};
#pragma unroll
          for (int d = 0; d < DD; d++) {
            float4 w4 = *(const float4*)(wL + d * VC + vb);
            v2f w0 = {w4.x, w4.x}, w1 = {w4.y, w4.y};
            v2f w2 = {w4.z, w4.z}, w3 = {w4.w, w4.w};
#pragma unroll
            for (int t = 0; t < 2; t++) {
              e2[t][0] = __builtin_elementwise_fma(ex2[t][d], w0, e2[t][0]);
              e2[t][1] = __builtin_elementwise_fma(ex2[t][d], w1, e2[t][1]);
              e2[t][2] = __builtin_elementwise_fma(ex2[t][d], w2, e2[t][2]);
              e2[t][3] = __builtin_elementwise_fma(ex2[t][d], w3, e2[t][3]);
            }
          }
          float4 bb = *(const float4*)(b1L + vb);
          float4 tb = *(const float4*)(t1L + vb);
          v2f bias0 = {fmaf(tt, tb.x, bb.x), fmaf(tt, tb.x, bb.x)};
          v2f bias1 = {fmaf(tt, tb.y, bb.y), fmaf(tt, tb.y, bb.y)};
          v2f bias2 = {fmaf(tt, tb.z, bb.z), fmaf(tt, tb.z, bb.z)};
          v2f bias3 = {fmaf(tt, tb.w, bb.w), fmaf(tt, tb.w, bb.w)};
          const v2f ks2 = {KS, KS};
#pragma unroll
          for (int t = 0; t < 2; t++) {
            e2[t][0] = __builtin_elementwise_fma(e2[t][0], ks2, bias0);
            e2[t][1] = __builtin_elementwise_fma(e2[t][1], ks2, bias1);
            e2[t][2] = __builtin_elementwise_fma(e2[t][2], ks2, bias2);
            e2[t][3] = __builtin_elementwise_fma(e2[t][3], ks2, bias3);
#pragma unroll
            for (int j = 0; j < 4; j++) {
              e2[t][j].x = exp2f(e2[t][j].x);
              e2[t][j].y = exp2f(e2[t][j].y);
            }
            l2[t] += (e2[t][0] + e2[t][1]) + (e2[t][2] + e2[t][3]);
          }
#pragma unroll
          for (int d = 0; d < DD; d++) {
            float4 c4 = *(const float4*)(cL + d * VC + vb);
            v2f c0 = {c4.x, c4.x}, c1 = {c4.y, c4.y};
            v2f c2 = {c4.z, c4.z}, c3 = {c4.w, c4.w};
#pragma unroll
            for (int t = 0; t < 2; t++) {
              v2f a = acc2[t][d];
              a = __builtin_elementwise_fma(e2[t][0], c0, a);
              a = __builtin_elementwise_fma(e2[t][1], c1, a);
              a = __builtin_elementwise_fma(e2[t][2], c2, a);
              a = __builtin_elementwise_fma(e2[t][3], c3, a);
              acc2[t][d] = a;
            }
          }
        }
      }
      // in-wave butterfly over the 32 lanes of each half — FULLY UNROLLED
#pragma unroll
      for (int t = 0; t < 2; t++) {
#pragma unroll
        for (int m = 1; m < 32; m <<= 1) {
          l2[t].x += __shfl_xor(l2[t].x, m, 64);
          l2[t].y += __shfl_xor(l2[t].y, m, 64);
        }
#pragma unroll
        for (int d = 0; d < DD; d++) {
#pragma unroll
          for (int m = 1; m < 32; m <<= 1) {
            acc2[t][d].x += __shfl_xor(acc2[t][d].x, m, 64);
            acc2[t][d].y += __shfl_xor(acc2[t][d].y, m, 64);
          }
        }
      }
      // cross-wave (pair) combine via LDS
      if (hl == 0) {
#pragma unroll
        for (int d = 0; d < DD; d += 2) {
          redP[wave][half][d >> 1] =
              make_float4(acc2[0][d].x, acc2[0][d].y, acc2[0][d + 1].x, acc2[0][d + 1].y);
          redP[wave][half][8 + (d >> 1)] =
              make_float4(acc2[1][d].x, acc2[1][d].y, acc2[1][d + 1].x, acc2[1][d + 1].y);
        }
        redP[wave][half][16] = make_float4(l2[0].x, l2[0].y, l2[1].x, l2[1].y);
      }
      __syncthreads();
      {
        const int pw = wave ^ 1;
#pragma unroll
        for (int d = 0; d < DD; d += 2) {
          float4 f0 = redP[pw][half][d >> 1];
          acc2[0][d].x += f0.x; acc2[0][d].y += f0.y;
          acc2[0][d + 1].x += f0.z; acc2[0][d + 1].y += f0.w;
          float4 f1 = redP[pw][half][8 + (d >> 1)];
          acc2[1][d].x += f1.x; acc2[1][d].y += f1.y;
          acc2[1][d + 1].x += f1.z; acc2[1][d + 1].y += f1.w;
        }
        float4 fl = redP[pw][half][16];
        l2[0].x += fl.x; l2[0].y += fl.y;
        l2[1].x += fl.z; l2[1].y += fl.w;
      }
      // epilogue: ex update — FULLY UNROLLED (both waves compute identically)
      const float inv1 = 1.0f / (1.0f - tt + 1e-10f);
      const float cf = (mh == 0) ? (0.5f * dt * inv1) : (dt * inv1);
#pragma unroll
      for (int t = 0; t < 2; t++) {
        const float ilx = 1.0f / l2[t].x, ily = 1.0f / l2[t].y;
#pragma unroll
        for (int d = 0; d < DD; d++) {
          const float mux = acc2[t][d].x * ilx, muy = acc2[t][d].y * ily;
          if (mh == 0) {
            ex2[t][d].x = fmaf(cf, mux - ex2[t][d].x, ex2[t][d].x);
            ex2[t][d].y = fmaf(cf, muy - ex2[t][d].y, ex2[t][d].y);
          } else {
            const float svx = sL[(sbase + t) * DD + d];
            const float svy = sL[(sbase + t + 2) * DD + d];
            ex2[t][d].x = fmaf(cf, mux - ex2[t][d].x, svx);
            ex2[t][d].y = fmaf(cf, muy - ex2[t][d].y, svy);
          }
        }
      }
      if (mh == 1) {
        __syncthreads();
        if (o == 0 && hl == 0) {
#pragma unroll
          for (int t = 0; t < 2; t++)
#pragma unroll
            for (int d = 0; d < DD; d++) {
              sL[(sbase + t) * DD + d]     = ex2[t][d].x;
              sL[(sbase + t + 2) * DD + d] = ex2[t][d].y;
            }
        }
      }
    }
  }

  // ---- VQ argmin: d = ||c||^2 - 2 x.c ; wave o sweeps codes [o*4096, +4096) ----
  v2f minv2[2];
  int minix[2], miniy[2];
#pragma unroll
  for (int t = 0; t < 2; t++) {
    minv2[t] = (v2f){3.402823466e38f, 3.402823466e38f};
    minix[t] = 0; miniy[t] = 0;
  }
#pragma unroll 1
  for (int p = 0; p < 32; p++) {
    const int v4 = (o << 12) + (p << 7) + (hl << 2);
    v2f dot2[2][4];
#pragma unroll
    for (int t = 0; t < 2; t++)
#pragma unroll
      for (int j = 0; j < 4; j++) dot2[t][j] = (v2f){0.f, 0.f};
#pragma unroll
    for (int d = 0; d < DD; d++) {
      float4 c4 = *(const float4*)(cbT + (size_t)d * VV + v4);   // L2-resident
      v2f c0 = {c4.x, c4.x}, c1 = {c4.y, c4.y};
      v2f c2 = {c4.z, c4.z}, c3 = {c4.w, c4.w};
#pragma unroll
      for (int t = 0; t < 2; t++) {
        dot2[t][0] = __builtin_elementwise_fma(ex2[t][d], c0, dot2[t][0]);
        dot2[t][1] = __builtin_elementwise_fma(ex2[t][d], c1, dot2[t][1]);
        dot2[t][2] = __builtin_elementwise_fma(ex2[t][d], c2, dot2[t][2]);
        dot2[t][3] = __builtin_elementwise_fma(ex2[t][d], c3, dot2[t][3]);
      }
    }
    float4 cc = *(const float4*)(CC2 + v4);
#pragma unroll
    for (int t = 0; t < 2; t++) {
#pragma unroll
      for (int j = 0; j < 4; j++) {
        const float ccj = (j == 0) ? cc.x : (j == 1) ? cc.y : (j == 2) ? cc.z : cc.w;
        float dx = fmaf(-2.f, dot2[t][j].x, ccj);
        float dy = fmaf(-2.f, dot2[t][j].y, ccj);
        if (dx < minv2[t].x) { minv2[t].x = dx; minix[t] = v4 + j; }
        if (dy < minv2[t].y) { minv2[t].y = dy; miniy[t] = v4 + j; }
      }
    }
  }
  // in-wave argmin butterfly (within half)
#pragma unroll
  for (int t = 0; t < 2; t++) {
#pragma unroll
    for (int m = 1; m < 32; m <<= 1) {
      float ovx = __shfl_xor(minv2[t].x, m, 64);
      int oix = __shfl_xor(minix[t], m, 64);
      if (ovx < minv2[t].x || (ovx == minv2[t].x && oix < minix[t])) {
        minv2[t].x = ovx; minix[t] = oix;
      }
      float ovy = __shfl_xor(minv2[t].y, m, 64);
      int oiy = __shfl_xor(miniy[t], m, 64);
      if (ovy < minv2[t].y || (ovy == minv2[t].y && oiy < miniy[t])) {
        minv2[t].y = ovy; miniy[t] = oiy;
      }
    }
  }
  // cross-wave argmin combine (tie -> smaller index; both waves converge)
  if (hl == 0) {
    redMv[wave][half][0] = minv2[0].x; redMi[wave][half][0] = minix[0];
    redMv[wave][half][1] = minv2[1].x; redMi[wave][half][1] = minix[1];
    redMv[wave][half][2] = minv2[0].y; redMi[wave][half][2] = miniy[0];
    redMv[wave][half][3] = minv2[1].y; redMi[wave][half][3] = miniy[1];
  }
  __syncthreads();
  {
    const int pw = wave ^ 1;
    float ov; int oi;
    ov = redMv[pw][half][0]; oi = redMi[pw][half][0];
    if (ov < minv2[0].x || (ov == minv2[0].x && oi < minix[0])) { minv2[0].x = ov; minix[0] = oi; }
    ov = redMv[pw][half][1]; oi = redMi[pw][half][1];
    if (ov < minv2[1].x || (ov == minv2[1].x && oi < minix[1])) { minv2[1].x = ov; minix[1] = oi; }
    ov = redMv[pw][half][2]; oi = redMi[pw][half][2];
    if (ov < minv2[0].y || (ov == minv2[0].y && oi < miniy[0])) { minv2[0].y = ov; miniy[0] = oi; }
    ov = redMv[pw][half][3]; oi = redMi[pw][half][3];
    if (ov < minv2[1].y || (ov == minv2[1].y && oi < miniy[1])) { minv2[1].y = ov; miniy[1] = oi; }
  }

  // ---- outputs (fp32): x_final (131072) then indices-as-float (8192) ----
  if (o == 0) {
#pragma unroll
    for (int t = 0; t < 2; t++) {
      if (hl == t) {
        const int tok = tokBase + t;
#pragma unroll
        for (int d = 0; d < DD; d++) out[(size_t)tok * DD + d] = ex2[t][d].x;
        out[(size_t)NTOK * DD + tok] = (float)minix[t];
      }
      if (hl == 2 + t) {
        const int tok = tokBase + t + 2;
#pragma unroll
        for (int d = 0; d < DD; d++) out[(size_t)tok * DD + d] = ex2[t][d].y;
        out[(size_t)NTOK * DD + tok] = (float)miniy[t];
      }
    }
  }
}

extern "C" void kernel_launch(void* const* d_in, const int* in_sizes, int n_in,
                              void* d_out, int out_size, void* d_ws, size_t ws_size,
                              hipStream_t stream) {
  const float* x0 = (const float*)d_in[0];
  const float* cb = (const float*)d_in[1];
  const float* Wm = (const float*)d_in[2];
  const float* bm = (const float*)d_in[3];
  const float* tp = (const float*)d_in[4];
  const int* ns   = (const int*)d_in[5];
  float* ws = (float*)d_ws;               // needs 622592 B
  float* out = (float*)d_out;             // fp32 outputs, concatenated flat

  prep_kernel<<<32, 256, 0, stream>>>(cb, bm, tp, ws);
  flow_kernel<<<256, 512, 0, stream>>>(x0, Wm, ws, ns, out);
}